// Round 5
// baseline (150.565 us; speedup 1.0000x reference)
//
#include <hip/hip_runtime.h>

#define NLAGC 20
#define NTC   100
#define DTC   0.01f
#define MU1C  0.06f
#define MU2C  0.02f
#define RC    0.02f
#define SIGC  0.2f
#define BETAC 0.05f
#define ETAC  0.5f
#define EPSC  1e-6f
#define UPENC 100.0f
#define YDECC 0.99004983374916805f   /* exp(-0.01) */
#define FDISCC 0.95122942450071403f  /* exp(-0.05) */
#define GEOMC 0.0081465072f          /* (1-exp(-0.01))*exp(-0.2) */

#define SPB 16    // samples per block (= MFMA M)
#define TPB 512   // 8 waves
#define NKT 4     // K tiles of 32 over h (K=128)
#define ZSTR 136  // z row stride in bf16 (128 h + 8 pad)

typedef __attribute__((ext_vector_type(8))) short short8v;
typedef __attribute__((ext_vector_type(4))) float f32x4;

__device__ __forceinline__ float sigm(float x){ return __builtin_amdgcn_rcpf(1.0f+__expf(-x)); }
__device__ __forceinline__ float tanhr(float x){ return 1.0f-2.0f*__builtin_amdgcn_rcpf(1.0f+__expf(2.0f*x)); }
__device__ __forceinline__ unsigned short f2bf(float f){            // RNE (staging)
    unsigned u=__float_as_uint(f);
    u += 0x7fffu + ((u>>16)&1u);
    return (unsigned short)(u>>16);
}
__device__ __forceinline__ unsigned short f2bf_rna(float f){        // 2-inst hot-path pack
    return (unsigned short)((__float_as_uint(f)+0x8000u)>>16);
}

__global__ __launch_bounds__(TPB,2) void polstm(
    const float* __restrict__ dw,  const float* __restrict__ xin,
    const float* __restrict__ Wf,  const float* __restrict__ bfp,
    const float* __restrict__ Wi,  const float* __restrict__ bip,
    const float* __restrict__ Wo,  const float* __restrict__ bop,
    const float* __restrict__ Wc,  const float* __restrict__ bcp,
    const float* __restrict__ Wpi, const float* __restrict__ bpi,
    float* __restrict__ out)
{
    __shared__ __align__(16) unsigned short zbuf[2][SPB*ZSTR];  // 8704 B h double-buffer
    __shared__ float dwl[SPB*NTC];                              // 6400 B
    __shared__ float xl[SPB*21];                                // 1344 B
    __shared__ __align__(16) float pibuf[2][SPB];               // pi exchange (wave 0 only)
    __shared__ __align__(16) float xcur[SPB];                   // current x, f32

    const int tid=threadIdx.x, w=tid>>6, lane=tid&63, col=lane&15, kg=lane>>4;
    const int j=w*16+col;                // hidden unit owned by this lane
    const int base=blockIdx.x*SPB;

    for(int e=tid;e<2*SPB*ZSTR;e+=TPB) ((unsigned short*)zbuf)[e]=0;
    for(int e=tid;e<SPB*NTC;e+=TPB) dwl[e]=dw[base*NTC+e];
    for(int e=tid;e<SPB*21;e+=TPB)  xl[e]=xin[base*21+e];

    // ---- weights -> register B-fragments (once) ----
    short8v bw[4][NKT], bpif[NKT];
    float wx[4], wt[4], bg[4];
    #pragma unroll
    for(int g=0;g<4;++g){
        const float* Wp=(g==0)?Wf:(g==1)?Wi:(g==2)?Wo:Wc;
        const float* bv=(g==0)?bfp:(g==1)?bip:(g==2)?bop:bcp;
        wx[g]=Wp[j]; wt[g]=Wp[129*128+j]; bg[g]=bv[j];
        #pragma unroll
        for(int kt=0;kt<NKT;++kt){
            short8v f;
            #pragma unroll
            for(int i=0;i<8;++i) f[i]=(short)f2bf(Wp[(1+kt*32+kg*8+i)*128+j]);
            bw[g][kt]=f;
        }
    }
    #pragma unroll
    for(int kt=0;kt<NKT;++kt){
        short8v f;
        #pragma unroll
        for(int i=0;i<8;++i){
            int k=kt*32+kg*8+i;
            int idx=k*2+((col<2)?col:0);
            float v=Wpi[idx];
            f[i]=(short)((col<2)?f2bf(v):(unsigned short)0);
        }
        bpif[kt]=f;
    }
    const float bp0=bpi[0], bp1=bpi[1];

    __syncthreads();                     // LDS staged

    // ---- per-lane state ----
    float C[4];
    #pragma unroll
    for(int r=0;r<4;++r) C[r]=(j==0)?xl[(kg*4+r)*21]:0.0f;

    float xs=0.f, ys=0.f, rew=0.f;       // wave 0, lane l<16 owns sample l
    if(w==0 && lane<SPB){
        float x0=xl[lane*21];
        xs=xl[lane*21+20];
        float acc=0.f;
        #pragma unroll
        for(int i=0;i<NLAGC;++i) acc+=__expf(-DTC*(float)(NLAGC-i))*xl[lane*21+1+i];
        ys=acc*DTC+GEOMC*x0;
    }
    if(j==0){                            // h0 = [x0, 0...0]
        #pragma unroll
        for(int r=0;r<4;++r) zbuf[0][(kg*4+r)*ZSTR+0]=f2bf(xl[(kg*4+r)*21]);
    }

    unsigned short* zr=zbuf[0];
    unsigned short* zw=zbuf[1];

    // ---- init phase: 20 steps, 1 barrier each ----
    #pragma unroll 1
    for(int m=0;m<NLAGC;++m){
        __syncthreads();
        short8v av[NKT];
        {   const unsigned short* zp=zr+col*ZSTR+kg*8;
            #pragma unroll
            for(int kt=0;kt<NKT;++kt) av[kt]=*(const short8v*)(zp+kt*32);
        }
        float tval=(float)(m-NLAGC)*DTC;
        float xr0=xl[(kg*4+0)*21+1+m], xr1=xl[(kg*4+1)*21+1+m];
        float xr2=xl[(kg*4+2)*21+1+m], xr3=xl[(kg*4+3)*21+1+m];
        float b0=fmaf(wt[0],tval,bg[0]), b1=fmaf(wt[1],tval,bg[1]);
        float b2=fmaf(wt[2],tval,bg[2]), b3=fmaf(wt[3],tval,bg[3]);
        f32x4 a0={fmaf(wx[0],xr0,b0),fmaf(wx[0],xr1,b0),fmaf(wx[0],xr2,b0),fmaf(wx[0],xr3,b0)};
        f32x4 a1={fmaf(wx[1],xr0,b1),fmaf(wx[1],xr1,b1),fmaf(wx[1],xr2,b1),fmaf(wx[1],xr3,b1)};
        f32x4 a2={fmaf(wx[2],xr0,b2),fmaf(wx[2],xr1,b2),fmaf(wx[2],xr2,b2),fmaf(wx[2],xr3,b2)};
        f32x4 a3={fmaf(wx[3],xr0,b3),fmaf(wx[3],xr1,b3),fmaf(wx[3],xr2,b3),fmaf(wx[3],xr3,b3)};
        #pragma unroll
        for(int kt=0;kt<NKT;++kt){
            a0=__builtin_amdgcn_mfma_f32_16x16x32_bf16(av[kt],bw[0][kt],a0,0,0,0);
            a1=__builtin_amdgcn_mfma_f32_16x16x32_bf16(av[kt],bw[1][kt],a1,0,0,0);
            a2=__builtin_amdgcn_mfma_f32_16x16x32_bf16(av[kt],bw[2][kt],a2,0,0,0);
            a3=__builtin_amdgcn_mfma_f32_16x16x32_bf16(av[kt],bw[3][kt],a3,0,0,0);
        }
        #pragma unroll
        for(int r=0;r<4;++r){
            C[r]=C[r]*sigm(a0[r])+tanhr(a3[r])*sigm(a1[r]);
            float h=sigm(a2[r])*tanhr(C[r]);
            zw[(kg*4+r)*ZSTR+j]=f2bf_rna(h);
        }
        unsigned short* tp=zr; zr=zw; zw=tp;
    }
    // x for main step 0
    if(w==0 && lane<SPB) xcur[lane]=xs;

    // ---- main phase: 100 steps, 2 barriers each ----
    #pragma unroll 1
    for(int t=0;t<NTC;++t){
        __syncthreads();                             // barrier1: zr (h) ready
        short8v av[NKT];
        {   const unsigned short* zp=zr+col*ZSTR+kg*8;
            #pragma unroll
            for(int kt=0;kt<NKT;++kt) av[kt]=*(const short8v*)(zp+kt*32);
        }
        // wave 0: pi chain first (critical path to xcur)
        if(w==0 && t>0){
            f32x4 a4={0.f,0.f,0.f,0.f};
            #pragma unroll
            for(int kt=0;kt<NKT;++kt)
                a4=__builtin_amdgcn_mfma_f32_16x16x32_bf16(av[kt],bpif[kt],a4,0,0,0);
            if(col<2) *(f32x4*)&pibuf[col][kg*4]=a4;
        }
        // all waves: gate MFMAs on h-part (independent of x)
        float tval=(float)t*DTC;
        float tb0=fmaf(wt[0],tval,bg[0]), tb1=fmaf(wt[1],tval,bg[1]);
        float tb2=fmaf(wt[2],tval,bg[2]), tb3=fmaf(wt[3],tval,bg[3]);
        f32x4 a0={tb0,tb0,tb0,tb0}, a1={tb1,tb1,tb1,tb1};
        f32x4 a2={tb2,tb2,tb2,tb2}, a3={tb3,tb3,tb3,tb3};
        #pragma unroll
        for(int kt=0;kt<NKT;++kt){
            a0=__builtin_amdgcn_mfma_f32_16x16x32_bf16(av[kt],bw[0][kt],a0,0,0,0);
            a1=__builtin_amdgcn_mfma_f32_16x16x32_bf16(av[kt],bw[1][kt],a1,0,0,0);
            a2=__builtin_amdgcn_mfma_f32_16x16x32_bf16(av[kt],bw[2][kt],a2,0,0,0);
            a3=__builtin_amdgcn_mfma_f32_16x16x32_bf16(av[kt],bw[3][kt],a3,0,0,0);
        }
        // wave 0: SDE for step t-1 -> x_t, write xcur
        if(w==0 && t>0 && lane<SPB){
            float p0=2.0f*sigm(pibuf[0][lane]+bp0);
            float p1=2.0f*sigm(pibuf[1][lane]+bp1);
            float disc=__expf(-BETAC*(float)(t-1)*DTC);
            float ir=__logf(fmaxf(p0*xs,0.f)+EPSC)*disc-fmaxf(-xs,0.f)*UPENC;
            rew+=ir*DTC;
            float dxv=((MU1C-RC)*p1-p0+RC)*xs+MU2C*ys;
            xs=xs+dxv*DTC+SIGC*xs*p1*dwl[lane*NTC+(t-1)];
            ys=ys*YDECC+xs*DTC;
            xcur[lane]=xs;
        }
        __syncthreads();                             // barrier2: xcur ready
        f32x4 xv=*(const f32x4*)&xcur[kg*4];
        #pragma unroll
        for(int r=0;r<4;++r){
            a0[r]=fmaf(wx[0],xv[r],a0[r]);
            a1[r]=fmaf(wx[1],xv[r],a1[r]);
            a2[r]=fmaf(wx[2],xv[r],a2[r]);
            a3[r]=fmaf(wx[3],xv[r],a3[r]);
        }
        #pragma unroll
        for(int r=0;r<4;++r){
            C[r]=C[r]*sigm(a0[r])+tanhr(a3[r])*sigm(a1[r]);
            float h=sigm(a2[r])*tanhr(C[r]);
            zw[(kg*4+r)*ZSTR+j]=f2bf_rna(h);
        }
        unsigned short* tp=zr; zr=zw; zw=tp;
    }

    // ---- epilogue: last SDE (step NTC-1) + final utility, wave 0 only ----
    __syncthreads();                                 // final h (zr) ready
    if(w==0){
        short8v av[NKT];
        {   const unsigned short* zp=zr+col*ZSTR+kg*8;
            #pragma unroll
            for(int kt=0;kt<NKT;++kt) av[kt]=*(const short8v*)(zp+kt*32);
        }
        f32x4 a4={0.f,0.f,0.f,0.f};
        #pragma unroll
        for(int kt=0;kt<NKT;++kt)
            a4=__builtin_amdgcn_mfma_f32_16x16x32_bf16(av[kt],bpif[kt],a4,0,0,0);
        if(col<2) *(f32x4*)&pibuf[col][kg*4]=a4;
        if(lane<SPB){
            float p0=2.0f*sigm(pibuf[0][lane]+bp0);
            float p1=2.0f*sigm(pibuf[1][lane]+bp1);
            float disc=__expf(-BETAC*(float)(NTC-1)*DTC);
            float ir=__logf(fmaxf(p0*xs,0.f)+EPSC)*disc-fmaxf(-xs,0.f)*UPENC;
            rew+=ir*DTC;
            float dxv=((MU1C-RC)*p1-p0+RC)*xs+MU2C*ys;
            xs=xs+dxv*DTC+SIGC*xs*p1*dwl[lane*NTC+(NTC-1)];
            ys=ys*YDECC+xs*DTC;
            rew+=__logf(fmaxf(xs+ETAC*ys,0.f)+EPSC)*(FDISCC/BETAC)-fmaxf(-xs,0.f)*UPENC;
            out[base+lane]=-rew;
        }
    }
}

extern "C" void kernel_launch(void* const* d_in, const int* in_sizes, int n_in,
                              void* d_out, int out_size, void* d_ws, size_t ws_size,
                              hipStream_t stream){
    const float* dw  = (const float*)d_in[0];
    const float* xin = (const float*)d_in[1];
    const float* Wf  = (const float*)d_in[2];
    const float* bf  = (const float*)d_in[3];
    const float* Wi  = (const float*)d_in[4];
    const float* bi  = (const float*)d_in[5];
    const float* Wo  = (const float*)d_in[6];
    const float* bo  = (const float*)d_in[7];
    const float* Wc  = (const float*)d_in[8];
    const float* bc  = (const float*)d_in[9];
    const float* Wpi = (const float*)d_in[10];
    const float* bpi = (const float*)d_in[11];
    float* out = (float*)d_out;
    int nblk = (out_size + SPB - 1) / SPB;   // 256
    polstm<<<dim3(nblk), dim3(TPB), 0, stream>>>(dw, xin, Wf, bf, Wi, bi, Wo, bo, Wc, bc, Wpi, bpi, out);
}